// Round 8
// baseline (66.203 us; speedup 1.0000x reference)
//
#include <hip/hip_runtime.h>
#include <math.h>

#define N_TOK 4096
#define BS 2
#define NHEAD 8
#define ROW 256                    // floats per token row (8 heads * 32)
#define NE 194560                  // edges per batch
#define PT_OFF 64                  // front pad (floats) for e0<0 reads
#define PT_SZ (NE * NHEAD + 128)   // per-batch pT floats incl front+back pad
#define STEPS 66                   // fwd: u=j+c, j<=62, c<=3 ; rev: v=u-3 in [-3,62]

// deg(i) = 32 + (i%32); rowptr(i) = 32i + 496*(i>>5) + r(r-1)/2
__device__ __forceinline__ int rowptr_a(int i) {
    const int r = i & 31;
    return 32 * i + 496 * (i >> 5) + ((r * (r - 1)) >> 1);
}

#if __has_builtin(__builtin_amdgcn_exp2f)
#define EXP2F(x) __builtin_amdgcn_exp2f(x)
#else
#define EXP2F(x) exp2f(x)
#endif

// 2048 blocks; wgid&7 ~ physical XCD: each XCD owns one batch and a contiguous
// 256-wide m-range -> its k/vf (or vb) row window (~1.5MB/tensor) fits 4MB L2.
__device__ __forceinline__ void map_block(int wg, int& b, int& m) {
    const int xcd = wg & 7;
    b = xcd & 1;
    m = ((xcd >> 1) << 8) + (wg >> 3);   // region*256 + slot, m in [0,1024)
}

// ---------------------------------------------------------------------------
// fwd: one block = 4 waves = job of 4 dsts {4m+7c} (bijection over tokens).
// Wave w handles steps u = w, w+4, ...; step u loads k/vf row r=4m+1+7u ONCE
// and applies it to 4 dst accumulators (slot j = u-c). p staged in LDS,
// flushed as coalesced edge-major [e][h] with 1/sum folded in. The p-staging
// buffer is then reused for the 4-wave accumulator merge (LDS stays ~12.7KB
// so 8 blocks/CU x 4 waves = full occupancy).
// ---------------------------------------------------------------------------
__global__ __launch_bounds__(256, 8)
void fwd_kernel(const float* __restrict__ vf, const float* __restrict__ q,
                const float* __restrict__ k, float* __restrict__ pT,
                float* __restrict__ vo) {
    int b, m; map_block(blockIdx.x, b, m);
    const int wid  = threadIdx.x >> 6;     // 0..3
    const int lane = threadIdx.x & 63;
    const int h    = lane >> 3;
    const int l8   = lane & 7;
    const int e4   = lane * 4;

    const size_t bstr = (size_t)N_TOK * ROW;
    const float* qb  = q  + b * bstr;
    const float* kb  = k  + b * bstr;
    const float* vfb = vf + b * bstr;

    const int d0 = 4 * m;
    int deg[4];
    float4 qv[4];
    #pragma unroll
    for (int c = 0; c < 4; ++c) {
        const int dstc = (d0 + 7 * c) & (N_TOK - 1);
        deg[c] = 32 + (dstc & 31);
        qv[c]  = *(const float4*)(qb + (size_t)dstc * ROW + e4);
    }

    // phase A: s_mem[0..2047] = s_p[c][j][h]; phase B: s_mem = part[3][4][256]
    __shared__ float s_mem[3 * 4 * ROW];
    __shared__ float s_s[4][4][NHEAD];
    __shared__ float s_inv[4][NHEAD];

    const float s2 = -0.25503494f;          // -1/sqrt(32) * log2(e)
    float4 acc[4];
    float  ssum[4];
    #pragma unroll
    for (int c = 0; c < 4; ++c) { acc[c] = make_float4(0.f,0.f,0.f,0.f); ssum[c] = 0.f; }

    const int deg_sel = 32 + (((d0 + 7 * l8) & (N_TOK - 1)) & 31);

    #pragma unroll 2
    for (int u = wid; u < STEPS; u += 4) {
        const int r = (d0 + 1 + 7 * u) & (N_TOK - 1);
        const float4 kv = *(const float4*)(kb  + (size_t)r * ROW + e4);
        const float4 fv = *(const float4*)(vfb + (size_t)r * ROW + e4);
        float p_sel = 0.f;
        #pragma unroll
        for (int c = 0; c < 4; ++c) {
            const int j = u - c;
            float d = fabsf(qv[c].x - kv.x) + fabsf(qv[c].y - kv.y)
                    + fabsf(qv[c].z - kv.z) + fabsf(qv[c].w - kv.w);
            d += __shfl_xor(d, 1, 8);
            d += __shfl_xor(d, 2, 8);
            d += __shfl_xor(d, 4, 8);       // 8-lane head group -> full L1 sum
            const float p = (j >= 0 && j < deg[c]) ? EXP2F(d * s2) : 0.f;
            ssum[c] += p;
            acc[c].x += p * fv.x; acc[c].y += p * fv.y;
            acc[c].z += p * fv.z; acc[c].w += p * fv.w;
            if (c == l8) p_sel = p;
        }
        const int jsel = u - l8;
        if (l8 < 4 && jsel >= 0 && jsel < deg_sel)
            s_mem[l8 * (64 * NHEAD) + jsel * NHEAD + h] = p_sel;  // s_p[c][j][h]
    }

    if (l8 == 0) {
        #pragma unroll
        for (int c = 0; c < 4; ++c) s_s[wid][c][h] = ssum[c];
    }
    __syncthreads();
    if (threadIdx.x < 32) {
        const int cc = threadIdx.x >> 3, hh = threadIdx.x & 7;
        s_inv[cc][hh] = 1.f / (s_s[0][cc][hh] + s_s[1][cc][hh] +
                               s_s[2][cc][hh] + s_s[3][cc][hh]);
    }
    __syncthreads();

    // pT flush: normalized weights, edge-major [e][h], coalesced runs.
    float* pTb = pT + (size_t)b * PT_SZ + PT_OFF;
    #pragma unroll
    for (int c = 0; c < 4; ++c) {
        const int dstc  = (d0 + 7 * c) & (N_TOK - 1);
        const int basec = rowptr_a(dstc);
        const int n     = (32 + (dstc & 31)) * NHEAD;
        float* dstp = pTb + (size_t)basec * NHEAD;
        const float* srcp = &s_mem[c * (64 * NHEAD)];
        for (int idx = threadIdx.x; idx < n; idx += 256)
            dstp[idx] = srcp[idx] * s_inv[c][idx & 7];
    }
    __syncthreads();   // s_p consumed; safe to reuse s_mem for the merge

    // merge: wave w owns c=w. Each wave writes acc[c] (c!=wid) to slot
    // (wid>c ? wid-1 : wid) of s_mem[c][3][256]; then sums its own c.
    #pragma unroll
    for (int c = 0; c < 4; ++c) {
        if (c != wid) {
            const int slot = (wid > c) ? wid - 1 : wid;
            *(float4*)(&s_mem[(c * 3 + slot) * ROW + e4]) = acc[c];
        }
    }
    __syncthreads();

    {
        const int c = wid;
        const int dstc = (d0 + 7 * c) & (N_TOK - 1);
        const float inv = s_inv[c][h];
        const float4 p0 = *(float4*)(&s_mem[(c * 3 + 0) * ROW + e4]);
        const float4 p1 = *(float4*)(&s_mem[(c * 3 + 1) * ROW + e4]);
        const float4 p2 = *(float4*)(&s_mem[(c * 3 + 2) * ROW + e4]);
        float4 o;
        o.x = (acc[c].x + p0.x + p1.x + p2.x) * inv;
        o.y = (acc[c].y + p0.y + p1.y + p2.y) * inv;
        o.z = (acc[c].z + p0.z + p1.z + p2.z) * inv;
        o.w = (acc[c].w + p0.w + p1.w + p2.w) * inv;
        *(float4*)(vo + b * bstr + (size_t)dstc * ROW + e4) = o;  // exclusive owner
    }
}

// ---------------------------------------------------------------------------
// rev: one block = 4 waves = job of 4 srcs {4m+7c}. Step u (v=u-3) loads vb
// row d = 4m-1-7v once; the 4 srcs' edges are e0..e0+3 (e0=rowptr(d)+v), so
// lanes 0..31 read 32 CONSECUTIVE floats of edge-major pT, distributed with
// width-64 shuffles. vo[src] += sum (exclusive owner, no atomics).
// ---------------------------------------------------------------------------
__global__ __launch_bounds__(256, 8)
void rev_kernel(const float* __restrict__ vb, const float* __restrict__ pT,
                float* __restrict__ vo) {
    int b, m; map_block(blockIdx.x, b, m);
    const int wid  = threadIdx.x >> 6;
    const int lane = threadIdx.x & 63;
    const int h    = lane >> 3;
    const int e4   = lane * 4;

    const size_t bstr = (size_t)N_TOK * ROW;
    const float* vbb = vb + b * bstr;
    const float* pTb = pT + (size_t)b * PT_SZ + PT_OFF;

    const int s0 = 4 * m;
    float4 acc[4];
    #pragma unroll
    for (int c = 0; c < 4; ++c) acc[c] = make_float4(0.f,0.f,0.f,0.f);

    #pragma unroll 2
    for (int u = wid; u < STEPS; u += 4) {
        const int v    = u - 3;                        // v in [-3, 62]
        const int d    = (s0 - 1 - 7 * v) & (N_TOK - 1);
        const int degd = 32 + (d & 31);
        const int e0   = rowptr_a(d) + v;              // e_c = e0 + c
        const float4 bv = *(const float4*)(vbb + (size_t)d * ROW + e4);
        // lanes 0..31: w for (c=lane>>3, h=lane&7); pads/invalid masked below
        const float pw = (lane < 32) ? pTb[(size_t)e0 * NHEAD + lane] : 0.f;
        #pragma unroll
        for (int c = 0; c < 4; ++c) {
            const int t = v + c;                       // slot index, valid < degd
            float w = __shfl(pw, c * 8 + h, 64);
            w = (t >= 0 && t < degd) ? w : 0.f;
            acc[c].x += w * bv.x; acc[c].y += w * bv.y;
            acc[c].z += w * bv.z; acc[c].w += w * bv.w;
        }
    }

    __shared__ float s_mem[3 * 4 * ROW];   // part[c][3][256]
    #pragma unroll
    for (int c = 0; c < 4; ++c) {
        if (c != wid) {
            const int slot = (wid > c) ? wid - 1 : wid;
            *(float4*)(&s_mem[(c * 3 + slot) * ROW + e4]) = acc[c];
        }
    }
    __syncthreads();

    {
        const int c = wid;
        const int src = (s0 + 7 * c) & (N_TOK - 1);
        float* vop = vo + b * bstr + (size_t)src * ROW + e4;
        const float4 p0 = *(float4*)(&s_mem[(c * 3 + 0) * ROW + e4]);
        const float4 p1 = *(float4*)(&s_mem[(c * 3 + 1) * ROW + e4]);
        const float4 p2 = *(float4*)(&s_mem[(c * 3 + 2) * ROW + e4]);
        float4 o = *(const float4*)vop;
        o.x += acc[c].x + p0.x + p1.x + p2.x;
        o.y += acc[c].y + p0.y + p1.y + p2.y;
        o.z += acc[c].z + p0.z + p1.z + p2.z;
        o.w += acc[c].w + p0.w + p1.w + p2.w;
        *(float4*)vop = o;
    }
}

extern "C" void kernel_launch(void* const* d_in, const int* in_sizes, int n_in,
                              void* d_out, int out_size, void* d_ws, size_t ws_size,
                              hipStream_t stream) {
    const float* vf = (const float*)d_in[0];
    const float* vb = (const float*)d_in[1];
    const float* q  = (const float*)d_in[2];
    const float* k  = (const float*)d_in[3];

    float* vo = (float*)d_out;
    float* pT = (float*)d_ws;   // BS * PT_SZ floats (~12.5MB)

    fwd_kernel<<<dim3(2048), dim3(256), 0, stream>>>(vf, q, k, pT, vo);
    rev_kernel<<<dim3(2048), dim3(256), 0, stream>>>(vb, pT, vo);
}

// Round 9
// 54.720 us; speedup vs baseline: 1.2098x; 1.2098x over previous
//
#include <hip/hip_runtime.h>
#include <math.h>

#define N_TOK 4096
#define BS 2
#define NHEAD 8
#define ROW 256                     // floats per token row (8 heads * 32)
#define NE 194560                   // edges per batch
#define PT_OFF 64                   // front pad (floats) for e0<0 reads
#define PT_SZ (NE * NHEAD + 1024)   // per-batch pT floats incl front+back pad
#define STEPS 66                    // fwd: u=j+c, j<=62, c<=3 ; rev: v=u-3 in [-3,62]

// deg(i) = 32 + (i%32); rowptr(i) = 32i + 496*(i>>5) + r(r-1)/2
__device__ __forceinline__ int rowptr_a(int i) {
    const int r = i & 31;
    return 32 * i + 496 * (i >> 5) + ((r * (r - 1)) >> 1);
}

#if __has_builtin(__builtin_amdgcn_exp2f)
#define EXP2F(x) __builtin_amdgcn_exp2f(x)
#else
#define EXP2F(x) exp2f(x)
#endif

// 2048 blocks; wgid&7 ~ physical XCD: each XCD owns one batch and a contiguous
// 256-wide m-range. With 128-thr blocks (~5 resident/CU) the instantaneous
// row window per XCD stays ~2MB < 4MB L2 (R8 showed 256-thr blocks blow it).
__device__ __forceinline__ void map_block(int wg, int& b, int& m) {
    const int xcd = wg & 7;
    b = xcd & 1;
    m = ((xcd >> 1) << 8) + (wg >> 3);   // region*256 + slot, m in [0,1024)
}

// ---------------------------------------------------------------------------
// fwd: one block = 2 waves = job of 4 dsts {4m+7c}. Wave w handles steps
// u = w, w+2, ...; step u loads k/vf row r=4m+1+7u ONCE and applies it to 4
// dst accumulators (slot j = u-c). Software pipeline depth 2: loads for step
// u+4 are issued before computing step u (indices are mod-4096 -> always
// legal; out-of-range steps' contributions are masked by j-bounds).
// ---------------------------------------------------------------------------
__global__ __launch_bounds__(128)
void fwd_kernel(const float* __restrict__ vf, const float* __restrict__ q,
                const float* __restrict__ k, float* __restrict__ pT,
                float* __restrict__ vo) {
    int b, m; map_block(blockIdx.x, b, m);
    const int wid  = threadIdx.x >> 6;
    const int lane = threadIdx.x & 63;
    const int h    = lane >> 3;
    const int l8   = lane & 7;
    const int e4   = lane * 4;

    const size_t bstr = (size_t)N_TOK * ROW;
    const float* qb  = q  + b * bstr;
    const float* kb  = k  + b * bstr;
    const float* vfb = vf + b * bstr;

    const int d0 = 4 * m;
    int deg[4];
    float4 qv[4];
    #pragma unroll
    for (int c = 0; c < 4; ++c) {
        const int dstc = (d0 + 7 * c) & (N_TOK - 1);
        deg[c] = 32 + (dstc & 31);
        qv[c]  = *(const float4*)(qb + (size_t)dstc * ROW + e4);
    }

    __shared__ float s_p[4][64][NHEAD];     // unnormalized p [c][j][h]
    __shared__ float s_acc[2][4][ROW];
    __shared__ float s_s[2][4][NHEAD];
    __shared__ float s_inv[4][NHEAD];

    const float s2 = -0.25503494f;          // -1/sqrt(32) * log2(e)
    float4 acc[4];
    float  ssum[4];
    #pragma unroll
    for (int c = 0; c < 4; ++c) { acc[c] = make_float4(0.f,0.f,0.f,0.f); ssum[c] = 0.f; }

    const int deg_sel = 32 + (((d0 + 7 * l8) & (N_TOK - 1)) & 31);

#define ROWOF(u) ((d0 + 1 + 7 * (u)) & (N_TOK - 1))
    // pipeline prologue: steps u and u+2 in flight
    {
        const int ra = ROWOF(wid), rb = ROWOF(wid + 2);
        (void)ra; (void)rb;
    }
    const int r0i = ROWOF(wid), r1i = ROWOF(wid + 2);
    float4 kv0 = *(const float4*)(kb  + (size_t)r0i * ROW + e4);
    float4 fv0 = *(const float4*)(vfb + (size_t)r0i * ROW + e4);
    float4 kv1 = *(const float4*)(kb  + (size_t)r1i * ROW + e4);
    float4 fv1 = *(const float4*)(vfb + (size_t)r1i * ROW + e4);

    for (int u = wid; u < STEPS; u += 2) {
        // prefetch step u+4 (always a legal wrapped row; value unused if OOB)
        const int rp = ROWOF(u + 4);
        const float4 kv2 = *(const float4*)(kb  + (size_t)rp * ROW + e4);
        const float4 fv2 = *(const float4*)(vfb + (size_t)rp * ROW + e4);

        float p_sel = 0.f;
        #pragma unroll
        for (int c = 0; c < 4; ++c) {
            const int j = u - c;
            float d = fabsf(qv[c].x - kv0.x) + fabsf(qv[c].y - kv0.y)
                    + fabsf(qv[c].z - kv0.z) + fabsf(qv[c].w - kv0.w);
            d += __shfl_xor(d, 1, 8);
            d += __shfl_xor(d, 2, 8);
            d += __shfl_xor(d, 4, 8);       // 8-lane head group -> full L1 sum
            const float p = (j >= 0 && j < deg[c]) ? EXP2F(d * s2) : 0.f;
            ssum[c] += p;
            acc[c].x += p * fv0.x; acc[c].y += p * fv0.y;
            acc[c].z += p * fv0.z; acc[c].w += p * fv0.w;
            if (c == l8) p_sel = p;         // compile-time c -> cndmask chain
        }
        const int jsel = u - l8;
        if (l8 < 4 && jsel >= 0 && jsel < deg_sel)
            s_p[l8][jsel][h] = p_sel;       // one half-exec ds_write per step

        kv0 = kv1; fv0 = fv1; kv1 = kv2; fv1 = fv2;
    }
#undef ROWOF

    #pragma unroll
    for (int c = 0; c < 4; ++c) {
        *(float4*)(&s_acc[wid][c][e4]) = acc[c];
        if (l8 == 0) s_s[wid][c][h] = ssum[c];
    }
    __syncthreads();
    if (threadIdx.x < 32) {
        const int cc = threadIdx.x >> 3, hh = threadIdx.x & 7;
        s_inv[cc][hh] = 1.f / (s_s[0][cc][hh] + s_s[1][cc][hh]);
    }
    __syncthreads();

    // vo rows: wave w finalizes c = 2w, 2w+1 (exclusive owner -> plain store)
    float* vob = vo + b * bstr;
    #pragma unroll
    for (int q2 = 0; q2 < 2; ++q2) {
        const int c = 2 * wid + q2;
        const int dstc = (d0 + 7 * c) & (N_TOK - 1);
        const float inv = s_inv[c][h];
        const float4 a0 = *(float4*)(&s_acc[0][c][e4]);
        const float4 a1 = *(float4*)(&s_acc[1][c][e4]);
        float4 o;
        o.x = (a0.x + a1.x) * inv;
        o.y = (a0.y + a1.y) * inv;
        o.z = (a0.z + a1.z) * inv;
        o.w = (a0.w + a1.w) * inv;
        *(float4*)(vob + (size_t)dstc * ROW + e4) = o;
    }

    // pT flush: normalized weights, edge-major [e][h], fully coalesced runs.
    float* pTb = pT + (size_t)b * PT_SZ + PT_OFF;
    #pragma unroll
    for (int c = 0; c < 4; ++c) {
        const int dstc  = (d0 + 7 * c) & (N_TOK - 1);
        const int basec = rowptr_a(dstc);
        const int n     = (32 + (dstc & 31)) * NHEAD;
        float* dstp = pTb + (size_t)basec * NHEAD;
        const float* srcp = &s_p[c][0][0];
        for (int idx = threadIdx.x; idx < n; idx += 128)
            dstp[idx] = srcp[idx] * s_inv[c][idx & 7];
    }
}

// ---------------------------------------------------------------------------
// rev: one block = 2 waves = job of 4 srcs {4m+7c}. Step u (v=u-3) loads vb
// row d = 4m-1-7v once; the 4 srcs' edges are e0..e0+3 (e0=rowptr(d)+v), so
// lanes 0..31 read 32 CONSECUTIVE floats of edge-major pT, distributed with
// width-64 shuffles. Same depth-2 software pipeline. pT pads absorb the
// prefetch overshoot (values masked by t-bounds before use).
// ---------------------------------------------------------------------------
__global__ __launch_bounds__(128)
void rev_kernel(const float* __restrict__ vb, const float* __restrict__ pT,
                float* __restrict__ vo) {
    int b, m; map_block(blockIdx.x, b, m);
    const int wid  = threadIdx.x >> 6;
    const int lane = threadIdx.x & 63;
    const int h    = lane >> 3;
    const int e4   = lane * 4;

    const size_t bstr = (size_t)N_TOK * ROW;
    const float* vbb = vb + b * bstr;
    const float* pTb = pT + (size_t)b * PT_SZ + PT_OFF;

    const int s0 = 4 * m;
    float4 acc[4];
    #pragma unroll
    for (int c = 0; c < 4; ++c) acc[c] = make_float4(0.f,0.f,0.f,0.f);

#define DOF(u) ((s0 - 1 - 7 * ((u) - 3)) & (N_TOK - 1))
    int dA = DOF(wid);
    int dB = DOF(wid + 2);
    {
        const int e0A = rowptr_a(dA) + (wid - 3);
        const int e0B = rowptr_a(dB) + (wid - 1);
        (void)e0A; (void)e0B;
    }
    float4 bv0, bv1; float pw0, pw1;
    {
        const int e0A = rowptr_a(dA) + (wid - 3);
        bv0 = *(const float4*)(vbb + (size_t)dA * ROW + e4);
        pw0 = (lane < 32) ? pTb[(size_t)e0A * NHEAD + lane] : 0.f;
        const int e0B = rowptr_a(dB) + (wid - 1);
        bv1 = *(const float4*)(vbb + (size_t)dB * ROW + e4);
        pw1 = (lane < 32) ? pTb[(size_t)e0B * NHEAD + lane] : 0.f;
    }

    for (int u = wid; u < STEPS; u += 2) {
        // prefetch step u+4
        const int dP  = DOF(u + 4);
        const int e0P = rowptr_a(dP) + (u + 1);        // (u+4)-3
        const float4 bv2 = *(const float4*)(vbb + (size_t)dP * ROW + e4);
        const float  pw2 = (lane < 32) ? pTb[(size_t)e0P * NHEAD + lane] : 0.f;

        const int v    = u - 3;
        const int degd = 32 + (dA & 31);
        #pragma unroll
        for (int c = 0; c < 4; ++c) {
            const int t = v + c;                       // slot index, valid < degd
            float w = __shfl(pw0, c * 8 + h, 64);
            w = (t >= 0 && t < degd) ? w : 0.f;
            acc[c].x += w * bv0.x; acc[c].y += w * bv0.y;
            acc[c].z += w * bv0.z; acc[c].w += w * bv0.w;
        }
        bv0 = bv1; pw0 = pw1; bv1 = bv2; pw1 = pw2;
        dA = dB; dB = dP;
    }
#undef DOF

    __shared__ float s_acc[2][4][ROW];
    #pragma unroll
    for (int c = 0; c < 4; ++c) *(float4*)(&s_acc[wid][c][e4]) = acc[c];
    __syncthreads();

    float* vob = vo + b * bstr;
    #pragma unroll
    for (int q2 = 0; q2 < 2; ++q2) {
        const int c = 2 * wid + q2;
        const int src = (s0 + 7 * c) & (N_TOK - 1);
        float* vop = vob + (size_t)src * ROW + e4;
        const float4 a0 = *(float4*)(&s_acc[0][c][e4]);
        const float4 a1 = *(float4*)(&s_acc[1][c][e4]);
        float4 o = *(const float4*)vop;
        o.x += a0.x + a1.x;
        o.y += a0.y + a1.y;
        o.z += a0.z + a1.z;
        o.w += a0.w + a1.w;
        *(float4*)vop = o;
    }
}

extern "C" void kernel_launch(void* const* d_in, const int* in_sizes, int n_in,
                              void* d_out, int out_size, void* d_ws, size_t ws_size,
                              hipStream_t stream) {
    const float* vf = (const float*)d_in[0];
    const float* vb = (const float*)d_in[1];
    const float* q  = (const float*)d_in[2];
    const float* k  = (const float*)d_in[3];

    float* vo = (float*)d_out;
    float* pT = (float*)d_ws;   // BS * PT_SZ floats (~12.5MB)

    fwd_kernel<<<dim3(2048), dim3(128), 0, stream>>>(vf, q, k, pT, vo);
    rev_kernel<<<dim3(2048), dim3(128), 0, stream>>>(vb, pT, vo);
}